// Round 1
// baseline (7660.175 us; speedup 1.0000x reference)
//
#include <hip/hip_runtime.h>

#define N_NODES   150000
#define N_EDGES   3000000
#define EMBED_DIM 64

// out = 0.25 * emb  (mean over {ego, l1, l2, l3} folded into per-term 0.25)
__global__ void cfgcn_init_out(const float4* __restrict__ emb,
                               float4* __restrict__ out, int n4) {
    int i = blockIdx.x * blockDim.x + threadIdx.x;
    if (i < n4) {
        float4 v = emb[i];
        out[i] = make_float4(0.25f * v.x, 0.25f * v.y, 0.25f * v.z, 0.25f * v.w);
    }
}

// out += 0.25 * agg
__global__ void cfgcn_accum_out(const float4* __restrict__ agg,
                                float4* __restrict__ out, int n4) {
    int i = blockIdx.x * blockDim.x + threadIdx.x;
    if (i < n4) {
        float4 v = agg[i];
        float4 o = out[i];
        o.x += 0.25f * v.x;
        o.y += 0.25f * v.y;
        o.z += 0.25f * v.z;
        o.w += 0.25f * v.w;
        out[i] = o;
    }
}

// One edge handled by 16 lanes; each lane owns 4 contiguous dims (float4).
// msg = sd[src]*sd[dst] * x[src]  scatter-added into agg[dst].
// (dst-side scale folded into the edge weight, so agg IS the next layer's ego.)
__global__ void cfgcn_edge_scatter(const float* __restrict__ x,
                                   const float* __restrict__ sd,
                                   const int* __restrict__ src,
                                   const int* __restrict__ dst,
                                   float* __restrict__ agg) {
    long long tid = (long long)blockIdx.x * blockDim.x + threadIdx.x;
    int e = (int)(tid >> 4);
    if (e >= N_EDGES) return;
    int d4 = ((int)tid & 15) << 2;

    int s = src[e];
    int d = dst[e];
    float w = sd[s] * sd[d];

    const float4 v = *reinterpret_cast<const float4*>(x + (size_t)s * EMBED_DIM + d4);
    float* p = agg + (size_t)d * EMBED_DIM + d4;

    unsafeAtomicAdd(p + 0, w * v.x);
    unsafeAtomicAdd(p + 1, w * v.y);
    unsafeAtomicAdd(p + 2, w * v.z);
    unsafeAtomicAdd(p + 3, w * v.w);
}

extern "C" void kernel_launch(void* const* d_in, const int* in_sizes, int n_in,
                              void* d_out, int out_size, void* d_ws, size_t ws_size,
                              hipStream_t stream) {
    const float* emb = (const float*)d_in[0];
    const float* sd  = (const float*)d_in[1];
    const int*   src = (const int*)d_in[2];
    const int*   dst = (const int*)d_in[3];
    float*       out = (float*)d_out;

    const size_t bufBytes = (size_t)N_NODES * EMBED_DIM * sizeof(float);  // 38.4 MB
    float* buf[2];
    buf[0] = (float*)d_ws;
    buf[1] = (float*)((char*)d_ws + bufBytes);

    const int n4 = N_NODES * EMBED_DIM / 4;           // 2.4M float4s
    const int nblk4 = (n4 + 255) / 256;

    cfgcn_init_out<<<nblk4, 256, 0, stream>>>((const float4*)emb, (float4*)out, n4);

    const float* x = emb;
    for (int l = 0; l < 3; ++l) {
        float* agg = buf[l & 1];
        hipMemsetAsync(agg, 0, bufBytes, stream);

        const long long tot = (long long)N_EDGES * 16;
        const int eblk = (int)((tot + 255) / 256);    // 187,500 blocks
        cfgcn_edge_scatter<<<eblk, 256, 0, stream>>>(x, sd, src, dst, agg);

        cfgcn_accum_out<<<nblk4, 256, 0, stream>>>((const float4*)agg, (float4*)out, n4);
        x = agg;
    }
}

// Round 2
// 670.337 us; speedup vs baseline: 11.4273x; 11.4273x over previous
//
#include <hip/hip_runtime.h>

#define N_NODES   150000
#define N_EDGES   3000000
#define EMBED_DIM 64
#define SCAN_BLOCK 256
#define N_SCAN_BLOCKS ((N_NODES + SCAN_BLOCK - 1) / SCAN_BLOCK)   // 586

// ---------- out = 0.25 * emb ----------
__global__ void k_init_out(const float4* __restrict__ emb, float4* __restrict__ out, int n4) {
    int i = blockIdx.x * blockDim.x + threadIdx.x;
    if (i < n4) {
        float4 v = emb[i];
        out[i] = make_float4(0.25f*v.x, 0.25f*v.y, 0.25f*v.z, 0.25f*v.w);
    }
}

// ---------- CSR build: histogram ----------
__global__ void k_hist(const int* __restrict__ dst, int* __restrict__ deg) {
    int e = blockIdx.x * blockDim.x + threadIdx.x;
    if (e < N_EDGES) atomicAdd(&deg[dst[e]], 1);
}

// ---------- scan stage 1: per-block sums ----------
__global__ void k_blocksum(const int* __restrict__ deg, int* __restrict__ bsum) {
    __shared__ int s[SCAN_BLOCK];
    int i = blockIdx.x * SCAN_BLOCK + threadIdx.x;
    s[threadIdx.x] = (i < N_NODES) ? deg[i] : 0;
    __syncthreads();
    for (int off = SCAN_BLOCK/2; off > 0; off >>= 1) {
        if (threadIdx.x < off) s[threadIdx.x] += s[threadIdx.x + off];
        __syncthreads();
    }
    if (threadIdx.x == 0) bsum[blockIdx.x] = s[0];
}

// ---------- scan stage 2: single-block exclusive scan of block sums ----------
__global__ void k_scan_bsums(int* __restrict__ bsum, int* __restrict__ rowptr) {
    __shared__ int s[1024];
    int t = threadIdx.x;
    int v = (t < N_SCAN_BLOCKS) ? bsum[t] : 0;
    s[t] = v;
    __syncthreads();
    for (int off = 1; off < 1024; off <<= 1) {
        int add = (t >= off) ? s[t - off] : 0;
        __syncthreads();
        s[t] += add;
        __syncthreads();
    }
    if (t < N_SCAN_BLOCKS) bsum[t] = s[t] - v;        // exclusive block offset
    if (t == 1023) rowptr[N_NODES] = s[1023];          // total edge count
}

// ---------- scan stage 3: final exclusive scan; writes rowptr and cursor ----------
__global__ void k_scan_final(const int* __restrict__ deg, const int* __restrict__ bsum,
                             int* __restrict__ rowptr, int* __restrict__ cursor) {
    __shared__ int s[SCAN_BLOCK];
    int i = blockIdx.x * SCAN_BLOCK + threadIdx.x;
    int t = threadIdx.x;
    int v = (i < N_NODES) ? deg[i] : 0;
    s[t] = v;
    __syncthreads();
    for (int off = 1; off < SCAN_BLOCK; off <<= 1) {
        int add = (t >= off) ? s[t - off] : 0;
        __syncthreads();
        s[t] += add;
        __syncthreads();
    }
    if (i < N_NODES) {
        int excl = s[t] - v + bsum[blockIdx.x];
        rowptr[i] = excl;
        cursor[i] = excl;
    }
}

// ---------- counting-sort scatter: srcw[pos] = {src, sd[src]*sd[dst]} ----------
__global__ void k_scatter(const int* __restrict__ src, const int* __restrict__ dst,
                          const float* __restrict__ sd,
                          int* __restrict__ cursor, int2* __restrict__ srcw) {
    int e = blockIdx.x * blockDim.x + threadIdx.x;
    if (e >= N_EDGES) return;
    int s = src[e], d = dst[e];
    int pos = atomicAdd(&cursor[d], 1);
    float w = sd[s] * sd[d];
    srcw[pos] = make_int2(s, __float_as_int(w));
}

// ---------- layer: wave-per-node gather; lanes = 4 edges x 16 dim-quads ----------
// agg[n] = sum_e w[e] * x[src[e]] ; out[n] += 0.25 * agg[n]
__global__ __launch_bounds__(256) void k_layer(const float4* __restrict__ x4,
                                               const int* __restrict__ rowptr,
                                               const int2* __restrict__ srcw,
                                               float4* __restrict__ agg4,
                                               float4* __restrict__ out4) {
    int wid = (blockIdx.x * blockDim.x + threadIdx.x) >> 6;   // node = wave id
    if (wid >= N_NODES) return;                                // wave-uniform exit
    int lane = threadIdx.x & 63;
    int ep = lane >> 4;     // edge slot 0..3
    int j  = lane & 15;     // float4 index within the 64-dim row

    int start = rowptr[wid];
    int end   = rowptr[wid + 1];

    float4 acc = make_float4(0.f, 0.f, 0.f, 0.f);
    for (int base = start; base < end; base += 4) {
        int ee = base + ep;
        int s = 0; float w = 0.f;
        if (ee < end) {
            int2 sw = srcw[ee];
            s = sw.x;
            w = __int_as_float(sw.y);
        }
        float4 v = x4[(size_t)s * 16 + j];
        acc.x += w * v.x; acc.y += w * v.y; acc.z += w * v.z; acc.w += w * v.w;
    }
    // reduce across the 4 edge slots (lane bits 4 and 5)
    #pragma unroll
    for (int m = 16; m <= 32; m <<= 1) {
        acc.x += __shfl_xor(acc.x, m, 64);
        acc.y += __shfl_xor(acc.y, m, 64);
        acc.z += __shfl_xor(acc.z, m, 64);
        acc.w += __shfl_xor(acc.w, m, 64);
    }
    if (ep == 0) {
        size_t idx = (size_t)wid * 16 + j;
        agg4[idx] = acc;
        float4 o = out4[idx];
        o.x += 0.25f*acc.x; o.y += 0.25f*acc.y; o.z += 0.25f*acc.z; o.w += 0.25f*acc.w;
        out4[idx] = o;
    }
}

extern "C" void kernel_launch(void* const* d_in, const int* in_sizes, int n_in,
                              void* d_out, int out_size, void* d_ws, size_t ws_size,
                              hipStream_t stream) {
    const float* emb = (const float*)d_in[0];
    const float* sd  = (const float*)d_in[1];
    const int*   src = (const int*)d_in[2];
    const int*   dst = (const int*)d_in[3];
    float*       out = (float*)d_out;

    // workspace layout (256 B aligned chunks)
    char* ws = (char*)d_ws;
    auto align256 = [](size_t x) { return (x + 255) & ~(size_t)255; };
    size_t off = 0;
    int* rowptr = (int*)(ws + off); off += align256((size_t)(N_NODES + 1) * 4);
    int* cursor = (int*)(ws + off); off += align256((size_t)N_NODES * 4);
    int* bsum   = (int*)(ws + off); off += align256((size_t)N_SCAN_BLOCKS * 4);
    int2* srcw  = (int2*)(ws + off); off += align256((size_t)N_EDGES * 8);
    float* buf0 = (float*)(ws + off); off += align256((size_t)N_NODES * EMBED_DIM * 4);
    float* buf1 = (float*)(ws + off);

    const int n4 = N_NODES * EMBED_DIM / 4;
    const int nblk4 = (n4 + 255) / 256;
    const int eblk  = (N_EDGES + 255) / 256;

    // out = 0.25 * emb
    k_init_out<<<nblk4, 256, 0, stream>>>((const float4*)emb, (float4*)out, n4);

    // ---- CSR build (once, reused by all 3 layers) ----
    hipMemsetAsync(cursor, 0, (size_t)N_NODES * 4, stream);          // cursor doubles as deg
    k_hist<<<eblk, 256, 0, stream>>>(dst, cursor);
    k_blocksum<<<N_SCAN_BLOCKS, SCAN_BLOCK, 0, stream>>>(cursor, bsum);
    k_scan_bsums<<<1, 1024, 0, stream>>>(bsum, rowptr);
    k_scan_final<<<N_SCAN_BLOCKS, SCAN_BLOCK, 0, stream>>>(cursor, bsum, rowptr, cursor);
    k_scatter<<<eblk, 256, 0, stream>>>(src, dst, sd, cursor, srcw);

    // ---- 3 layers, gather-only ----
    const int lblk = (N_NODES + 3) / 4;   // 4 waves/block, 1 node/wave
    const float* x = emb;
    float* bufs[2] = { buf0, buf1 };
    for (int l = 0; l < 3; ++l) {
        float* agg = bufs[l & 1];
        k_layer<<<lblk, 256, 0, stream>>>((const float4*)x, rowptr, srcw,
                                          (float4*)agg, (float4*)out);
        x = agg;
    }
}

// Round 3
// 514.297 us; speedup vs baseline: 14.8944x; 1.3034x over previous
//
#include <hip/hip_runtime.h>

#define N_NODES   150000
#define N_EDGES   3000000
#define EMBED_DIM 64
#define SCAN_BLOCK 256
#define N_SCAN_BLOCKS ((N_NODES + SCAN_BLOCK - 1) / SCAN_BLOCK)   // 586

typedef unsigned int uint;

// ---- bf16 helpers (RNE pack, shift unpack) ----
__device__ inline uint pack2_bf16(float a, float b) {
    uint ua = __float_as_uint(a);
    uint ub = __float_as_uint(b);
    ua += 0x7fffu + ((ua >> 16) & 1u);
    ub += 0x7fffu + ((ub >> 16) & 1u);
    return (ua >> 16) | (ub & 0xffff0000u);
}
// acc[k] += w*lo(u); acc[k+1] += w*hi(u)
#define FMA2(u, A0, A1)                                        \
    {   float _lo = __uint_as_float((u) << 16);                \
        float _hi = __uint_as_float((u) & 0xffff0000u);        \
        (A0) += w * _lo;  (A1) += w * _hi; }

// ---------- fp32 -> bf16 convert (4 elems/thread) ----------
__global__ void k_to_bf16(const float4* __restrict__ in, uint2* __restrict__ out, int n4) {
    int i = blockIdx.x * blockDim.x + threadIdx.x;
    if (i < n4) {
        float4 v = in[i];
        out[i] = make_uint2(pack2_bf16(v.x, v.y), pack2_bf16(v.z, v.w));
    }
}

// ---------- CSR build: histogram ----------
__global__ void k_hist(const int* __restrict__ dst, int* __restrict__ deg) {
    int e = blockIdx.x * blockDim.x + threadIdx.x;
    if (e < N_EDGES) atomicAdd(&deg[dst[e]], 1);
}

// ---------- scan stage 1: per-block sums ----------
__global__ void k_blocksum(const int* __restrict__ deg, int* __restrict__ bsum) {
    __shared__ int s[SCAN_BLOCK];
    int i = blockIdx.x * SCAN_BLOCK + threadIdx.x;
    s[threadIdx.x] = (i < N_NODES) ? deg[i] : 0;
    __syncthreads();
    for (int off = SCAN_BLOCK / 2; off > 0; off >>= 1) {
        if (threadIdx.x < off) s[threadIdx.x] += s[threadIdx.x + off];
        __syncthreads();
    }
    if (threadIdx.x == 0) bsum[blockIdx.x] = s[0];
}

// ---------- scan stage 2: single-block exclusive scan of block sums ----------
__global__ void k_scan_bsums(int* __restrict__ bsum, int* __restrict__ rowptr) {
    __shared__ int s[1024];
    int t = threadIdx.x;
    int v = (t < N_SCAN_BLOCKS) ? bsum[t] : 0;
    s[t] = v;
    __syncthreads();
    for (int off = 1; off < 1024; off <<= 1) {
        int add = (t >= off) ? s[t - off] : 0;
        __syncthreads();
        s[t] += add;
        __syncthreads();
    }
    if (t < N_SCAN_BLOCKS) bsum[t] = s[t] - v;
    if (t == 1023) rowptr[N_NODES] = s[1023];
}

// ---------- scan stage 3: final exclusive scan; writes rowptr and cursor ----------
__global__ void k_scan_final(const int* __restrict__ deg, const int* __restrict__ bsum,
                             int* __restrict__ rowptr, int* __restrict__ cursor) {
    __shared__ int s[SCAN_BLOCK];
    int i = blockIdx.x * SCAN_BLOCK + threadIdx.x;
    int t = threadIdx.x;
    int v = (i < N_NODES) ? deg[i] : 0;
    s[t] = v;
    __syncthreads();
    for (int off = 1; off < SCAN_BLOCK; off <<= 1) {
        int add = (t >= off) ? s[t - off] : 0;
        __syncthreads();
        s[t] += add;
        __syncthreads();
    }
    if (i < N_NODES) {
        int excl = s[t] - v + bsum[blockIdx.x];
        rowptr[i] = excl;
        cursor[i] = excl;
    }
}

// ---------- counting-sort scatter: srcw[pos] = {src, sd[src]*sd[dst]} ----------
__global__ void k_scatter(const int* __restrict__ src, const int* __restrict__ dst,
                          const float* __restrict__ sd,
                          int* __restrict__ cursor, int2* __restrict__ srcw) {
    int e = blockIdx.x * blockDim.x + threadIdx.x;
    if (e >= N_EDGES) return;
    int s = src[e], d = dst[e];
    int pos = atomicAdd(&cursor[d], 1);
    float w = sd[s] * sd[d];
    srcw[pos] = make_int2(s, __float_as_int(w));
}

// ---------- layer: wave-per-node gather over bf16 rows ----------
// lanes = 8 edge-slots x 8 chunk-lanes; each lane loads 16B = 8 bf16 of x[src].
// agg[n] = sum_e w_e * x[src_e]  (fp32 accum, bf16 store)
__global__ __launch_bounds__(256) void k_layer(const uint4* __restrict__ xb,
                                               const int* __restrict__ rowptr,
                                               const int2* __restrict__ srcw,
                                               uint4* __restrict__ aggb) {
    int wid = (blockIdx.x * blockDim.x + threadIdx.x) >> 6;
    if (wid >= N_NODES) return;                 // wave-uniform exit
    int lane = threadIdx.x & 63;
    int ep = lane >> 3;     // edge slot 0..7
    int j  = lane & 7;      // 16B chunk (dims j*8 .. j*8+7)

    int start = rowptr[wid];
    int end   = rowptr[wid + 1];

    float a0 = 0.f, a1 = 0.f, a2 = 0.f, a3 = 0.f;
    float a4 = 0.f, a5 = 0.f, a6 = 0.f, a7 = 0.f;
    for (int base = start; base < end; base += 8) {
        int ee = base + ep;
        if (ee < end) {
            int2 sw = srcw[ee];
            float w = __int_as_float(sw.y);
            uint4 v = xb[(size_t)sw.x * 8 + j];
            FMA2(v.x, a0, a1);
            FMA2(v.y, a2, a3);
            FMA2(v.z, a4, a5);
            FMA2(v.w, a6, a7);
        }
    }
    // reduce across the 8 edge slots (lane bits 3,4,5)
    #pragma unroll
    for (int m = 8; m <= 32; m <<= 1) {
        a0 += __shfl_xor(a0, m, 64);
        a1 += __shfl_xor(a1, m, 64);
        a2 += __shfl_xor(a2, m, 64);
        a3 += __shfl_xor(a3, m, 64);
        a4 += __shfl_xor(a4, m, 64);
        a5 += __shfl_xor(a5, m, 64);
        a6 += __shfl_xor(a6, m, 64);
        a7 += __shfl_xor(a7, m, 64);
    }
    if (ep == 0) {
        uint4 r;
        r.x = pack2_bf16(a0, a1);
        r.y = pack2_bf16(a2, a3);
        r.z = pack2_bf16(a4, a5);
        r.w = pack2_bf16(a6, a7);
        aggb[(size_t)wid * 8 + j] = r;
    }
}

// ---------- final: out = 0.25*(emb + a1 + a2 + a3) ----------
__global__ void k_combine(const float4* __restrict__ emb,
                          const uint2* __restrict__ b1,
                          const uint2* __restrict__ b2,
                          const uint2* __restrict__ b3,
                          float4* __restrict__ out, int n4) {
    int i = blockIdx.x * blockDim.x + threadIdx.x;
    if (i >= n4) return;
    float4 e = emb[i];
    uint2 u1 = b1[i], u2 = b2[i], u3 = b3[i];
    float4 o;
    o.x = e.x + __uint_as_float(u1.x << 16)        + __uint_as_float(u2.x << 16)        + __uint_as_float(u3.x << 16);
    o.y = e.y + __uint_as_float(u1.x & 0xffff0000u) + __uint_as_float(u2.x & 0xffff0000u) + __uint_as_float(u3.x & 0xffff0000u);
    o.z = e.z + __uint_as_float(u1.y << 16)        + __uint_as_float(u2.y << 16)        + __uint_as_float(u3.y << 16);
    o.w = e.w + __uint_as_float(u1.y & 0xffff0000u) + __uint_as_float(u2.y & 0xffff0000u) + __uint_as_float(u3.y & 0xffff0000u);
    o.x *= 0.25f; o.y *= 0.25f; o.z *= 0.25f; o.w *= 0.25f;
    out[i] = o;
}

extern "C" void kernel_launch(void* const* d_in, const int* in_sizes, int n_in,
                              void* d_out, int out_size, void* d_ws, size_t ws_size,
                              hipStream_t stream) {
    const float* emb = (const float*)d_in[0];
    const float* sd  = (const float*)d_in[1];
    const int*   src = (const int*)d_in[2];
    const int*   dst = (const int*)d_in[3];
    float*       out = (float*)d_out;

    char* ws = (char*)d_ws;
    auto align256 = [](size_t x) { return (x + 255) & ~(size_t)255; };
    size_t off = 0;
    int*  rowptr = (int*)(ws + off);  off += align256((size_t)(N_NODES + 1) * 4);
    int*  cursor = (int*)(ws + off);  off += align256((size_t)N_NODES * 4);
    int*  bsum   = (int*)(ws + off);  off += align256((size_t)N_SCAN_BLOCKS * 4);
    int2* srcw   = (int2*)(ws + off); off += align256((size_t)N_EDGES * 8);
    const size_t rowBytes = (size_t)N_NODES * EMBED_DIM * 2;   // bf16 rows, 19.2 MB
    uint* xb0 = (uint*)(ws + off);    off += align256(rowBytes);
    uint* ag1 = (uint*)(ws + off);    off += align256(rowBytes);
    uint* ag2 = (uint*)(ws + off);    off += align256(rowBytes);
    uint* ag3 = (uint*)(ws + off);

    const int n4 = N_NODES * EMBED_DIM / 4;       // 2.4M
    const int nblk4 = (n4 + 255) / 256;
    const int eblk  = (N_EDGES + 255) / 256;

    // ---- CSR build ----
    hipMemsetAsync(cursor, 0, (size_t)N_NODES * 4, stream);     // cursor doubles as deg
    k_hist<<<eblk, 256, 0, stream>>>(dst, cursor);
    k_blocksum<<<N_SCAN_BLOCKS, SCAN_BLOCK, 0, stream>>>(cursor, bsum);
    k_scan_bsums<<<1, 1024, 0, stream>>>(bsum, rowptr);
    k_scan_final<<<N_SCAN_BLOCKS, SCAN_BLOCK, 0, stream>>>(cursor, bsum, rowptr, cursor);
    k_scatter<<<eblk, 256, 0, stream>>>(src, dst, sd, cursor, srcw);

    // ---- emb -> bf16 ----
    k_to_bf16<<<nblk4, 256, 0, stream>>>((const float4*)emb, (uint2*)xb0, n4);

    // ---- 3 layers, gather-only, bf16 in/out ----
    const int lblk = (N_NODES + 3) / 4;           // 4 waves/block
    uint* aggs[3] = { ag1, ag2, ag3 };
    const uint* x = xb0;
    for (int l = 0; l < 3; ++l) {
        k_layer<<<lblk, 256, 0, stream>>>((const uint4*)x, rowptr, srcw, (uint4*)aggs[l]);
        x = aggs[l];
    }

    // ---- combine ----
    k_combine<<<nblk4, 256, 0, stream>>>((const float4*)emb, (const uint2*)ag1,
                                         (const uint2*)ag2, (const uint2*)ag3,
                                         (float4*)out, n4);
}

// Round 4
// 451.898 us; speedup vs baseline: 16.9511x; 1.1381x over previous
//
#include <hip/hip_runtime.h>

#define N_NODES   150000
#define N_EDGES   3000000
#define EMBED_DIM 64
#define SCAN_BLOCK 256
#define N_SCAN_BLOCKS ((N_NODES + SCAN_BLOCK - 1) / SCAN_BLOCK)   // 586
#define N_UNITS   (N_EDGES / 4)                                   // 750000 int4 units
#define NODES_PER_REGION (N_NODES / 8)                            // 18750

typedef unsigned int uint;

// ---- bf16 helpers (RNE pack, shift unpack) ----
__device__ inline uint pack2_bf16(float a, float b) {
    uint ua = __float_as_uint(a);
    uint ub = __float_as_uint(b);
    ua += 0x7fffu + ((ua >> 16) & 1u);
    ub += 0x7fffu + ((ub >> 16) & 1u);
    return (ua >> 16) | (ub & 0xffff0000u);
}
#define FMA2(u, A0, A1)                                        \
    {   float _lo = __uint_as_float((u) << 16);                \
        float _hi = __uint_as_float((u) & 0xffff0000u);        \
        (A0) += w * _lo;  (A1) += w * _hi; }

// ---------- fp32 -> bf16 convert ----------
__global__ void k_to_bf16(const float4* __restrict__ in, uint2* __restrict__ out, int n4) {
    int i = blockIdx.x * blockDim.x + threadIdx.x;
    if (i < n4) {
        float4 v = in[i];
        out[i] = make_uint2(pack2_bf16(v.x, v.y), pack2_bf16(v.z, v.w));
    }
}

// ---------- histogram + per-edge rank: ranksrc[e] = (rank<<20) | src ----------
__global__ void k_hist_rank(const int4* __restrict__ dst4, const int4* __restrict__ src4,
                            uint* __restrict__ deg, uint4* __restrict__ ranksrc4) {
    int u = blockIdx.x * blockDim.x + threadIdx.x;
    if (u >= N_UNITS) return;
    int4 d = dst4[u];
    int4 s = src4[u];
    uint r0 = atomicAdd(&deg[d.x], 1u);
    uint r1 = atomicAdd(&deg[d.y], 1u);
    uint r2 = atomicAdd(&deg[d.z], 1u);
    uint r3 = atomicAdd(&deg[d.w], 1u);
    uint4 o;
    o.x = (r0 << 20) | (uint)s.x;
    o.y = (r1 << 20) | (uint)s.y;
    o.z = (r2 << 20) | (uint)s.z;
    o.w = (r3 << 20) | (uint)s.w;
    ranksrc4[u] = o;
}

// ---------- scan stage 1: per-block sums ----------
__global__ void k_blocksum(const uint* __restrict__ deg, int* __restrict__ bsum) {
    __shared__ int s[SCAN_BLOCK];
    int i = blockIdx.x * SCAN_BLOCK + threadIdx.x;
    s[threadIdx.x] = (i < N_NODES) ? (int)deg[i] : 0;
    __syncthreads();
    for (int off = SCAN_BLOCK / 2; off > 0; off >>= 1) {
        if (threadIdx.x < off) s[threadIdx.x] += s[threadIdx.x + off];
        __syncthreads();
    }
    if (threadIdx.x == 0) bsum[blockIdx.x] = s[0];
}

// ---------- scan stage 2: single-block exclusive scan of block sums ----------
__global__ void k_scan_bsums(int* __restrict__ bsum) {
    __shared__ int s[1024];
    int t = threadIdx.x;
    int v = (t < N_SCAN_BLOCKS) ? bsum[t] : 0;
    s[t] = v;
    __syncthreads();
    for (int off = 1; off < 1024; off <<= 1) {
        int add = (t >= off) ? s[t - off] : 0;
        __syncthreads();
        s[t] += add;
        __syncthreads();
    }
    if (t < N_SCAN_BLOCKS) bsum[t] = s[t] - v;
}

// ---------- scan stage 3: final exclusive scan -> rowptr ----------
__global__ void k_scan_final(const uint* __restrict__ deg, const int* __restrict__ bsum,
                             int* __restrict__ rowptr) {
    __shared__ int s[SCAN_BLOCK];
    int i = blockIdx.x * SCAN_BLOCK + threadIdx.x;
    int t = threadIdx.x;
    int v = (i < N_NODES) ? (int)deg[i] : 0;
    s[t] = v;
    __syncthreads();
    for (int off = 1; off < SCAN_BLOCK; off <<= 1) {
        int add = (t >= off) ? s[t - off] : 0;
        __syncthreads();
        s[t] += add;
        __syncthreads();
    }
    if (i < N_NODES) rowptr[i] = s[t] - v + bsum[blockIdx.x];
}

// ---------- XCD-homed, atomic-free CSR scatter ----------
// Block group g = bid&7 handles only dst-region g (18750 nodes), so all writes to
// that 3MB srcw region come from one XCD's L2 -> full line merge before writeback.
__global__ __launch_bounds__(256) void k_scatter_swz(const int4* __restrict__ dst4,
                                                     const uint4* __restrict__ rs4,
                                                     const float* __restrict__ sd,
                                                     const int* __restrict__ rowptr,
                                                     int2* __restrict__ srcw) {
    const int  grp = blockIdx.x & 7;
    const int  lo  = grp * NODES_PER_REGION;
    const int  bIn = blockIdx.x >> 3;
    const int  nBIn = (int)gridDim.x >> 3;
    const int  stride = nBIn * 256;

    for (int u = bIn * 256 + (int)threadIdx.x; u < N_UNITS; u += stride) {
        int4 d = dst4[u];
        bool m0 = (uint)(d.x - lo) < (uint)NODES_PER_REGION;
        bool m1 = (uint)(d.y - lo) < (uint)NODES_PER_REGION;
        bool m2 = (uint)(d.z - lo) < (uint)NODES_PER_REGION;
        bool m3 = (uint)(d.w - lo) < (uint)NODES_PER_REGION;
        if (m0 | m1 | m2 | m3) {
            uint4 rs = rs4[u];
            if (m0) { uint s = rs.x & 0xFFFFFu, r = rs.x >> 20;
                      float w = sd[s] * sd[d.x];
                      srcw[rowptr[d.x] + (int)r] = make_int2((int)s, __float_as_int(w)); }
            if (m1) { uint s = rs.y & 0xFFFFFu, r = rs.y >> 20;
                      float w = sd[s] * sd[d.y];
                      srcw[rowptr[d.y] + (int)r] = make_int2((int)s, __float_as_int(w)); }
            if (m2) { uint s = rs.z & 0xFFFFFu, r = rs.z >> 20;
                      float w = sd[s] * sd[d.z];
                      srcw[rowptr[d.z] + (int)r] = make_int2((int)s, __float_as_int(w)); }
            if (m3) { uint s = rs.w & 0xFFFFFu, r = rs.w >> 20;
                      float w = sd[s] * sd[d.w];
                      srcw[rowptr[d.w] + (int)r] = make_int2((int)s, __float_as_int(w)); }
        }
    }
}

// ---------- layer: wave-per-node gather over bf16 rows ----------
__global__ __launch_bounds__(256) void k_layer(const uint4* __restrict__ xb,
                                               const int* __restrict__ rowptr,
                                               const int2* __restrict__ srcw,
                                               uint4* __restrict__ aggb) {
    int wid = (blockIdx.x * blockDim.x + threadIdx.x) >> 6;
    if (wid >= N_NODES) return;                 // wave-uniform exit
    int lane = threadIdx.x & 63;
    int ep = lane >> 3;     // edge slot 0..7
    int j  = lane & 7;      // 16B chunk (dims j*8 .. j*8+7)

    int start = rowptr[wid];
    int end   = (wid + 1 < N_NODES) ? rowptr[wid + 1] : N_EDGES;

    float a0 = 0.f, a1 = 0.f, a2 = 0.f, a3 = 0.f;
    float a4 = 0.f, a5 = 0.f, a6 = 0.f, a7 = 0.f;
    for (int base = start; base < end; base += 8) {
        int ee = base + ep;
        if (ee < end) {
            int2 sw = srcw[ee];
            float w = __int_as_float(sw.y);
            uint4 v = xb[(size_t)sw.x * 8 + j];
            FMA2(v.x, a0, a1);
            FMA2(v.y, a2, a3);
            FMA2(v.z, a4, a5);
            FMA2(v.w, a6, a7);
        }
    }
    #pragma unroll
    for (int m = 8; m <= 32; m <<= 1) {
        a0 += __shfl_xor(a0, m, 64);
        a1 += __shfl_xor(a1, m, 64);
        a2 += __shfl_xor(a2, m, 64);
        a3 += __shfl_xor(a3, m, 64);
        a4 += __shfl_xor(a4, m, 64);
        a5 += __shfl_xor(a5, m, 64);
        a6 += __shfl_xor(a6, m, 64);
        a7 += __shfl_xor(a7, m, 64);
    }
    if (ep == 0) {
        uint4 r;
        r.x = pack2_bf16(a0, a1);
        r.y = pack2_bf16(a2, a3);
        r.z = pack2_bf16(a4, a5);
        r.w = pack2_bf16(a6, a7);
        aggb[(size_t)wid * 8 + j] = r;
    }
}

// ---------- final: out = 0.25*(emb + a1 + a2 + a3) ----------
__global__ void k_combine(const float4* __restrict__ emb,
                          const uint2* __restrict__ b1,
                          const uint2* __restrict__ b2,
                          const uint2* __restrict__ b3,
                          float4* __restrict__ out, int n4) {
    int i = blockIdx.x * blockDim.x + threadIdx.x;
    if (i >= n4) return;
    float4 e = emb[i];
    uint2 u1 = b1[i], u2 = b2[i], u3 = b3[i];
    float4 o;
    o.x = e.x + __uint_as_float(u1.x << 16)         + __uint_as_float(u2.x << 16)         + __uint_as_float(u3.x << 16);
    o.y = e.y + __uint_as_float(u1.x & 0xffff0000u) + __uint_as_float(u2.x & 0xffff0000u) + __uint_as_float(u3.x & 0xffff0000u);
    o.z = e.z + __uint_as_float(u1.y << 16)         + __uint_as_float(u2.y << 16)         + __uint_as_float(u3.y << 16);
    o.w = e.w + __uint_as_float(u1.y & 0xffff0000u) + __uint_as_float(u2.y & 0xffff0000u) + __uint_as_float(u3.y & 0xffff0000u);
    o.x *= 0.25f; o.y *= 0.25f; o.z *= 0.25f; o.w *= 0.25f;
    out[i] = o;
}

extern "C" void kernel_launch(void* const* d_in, const int* in_sizes, int n_in,
                              void* d_out, int out_size, void* d_ws, size_t ws_size,
                              hipStream_t stream) {
    const float* emb = (const float*)d_in[0];
    const float* sd  = (const float*)d_in[1];
    const int*   src = (const int*)d_in[2];
    const int*   dst = (const int*)d_in[3];
    float*       out = (float*)d_out;

    char* ws = (char*)d_ws;
    auto align256 = [](size_t x) { return (x + 255) & ~(size_t)255; };
    size_t off = 0;
    int*  rowptr  = (int*)(ws + off);  off += align256((size_t)N_NODES * 4);
    uint* deg     = (uint*)(ws + off); off += align256((size_t)N_NODES * 4);
    int*  bsum    = (int*)(ws + off);  off += align256((size_t)N_SCAN_BLOCKS * 4);
    uint* ranksrc = (uint*)(ws + off); off += align256((size_t)N_EDGES * 4);     // 12 MB
    int2* srcw    = (int2*)(ws + off); off += align256((size_t)N_EDGES * 8);     // 24 MB
    const size_t rowBytes = (size_t)N_NODES * EMBED_DIM * 2;                     // 19.2 MB
    uint* buf0 = (uint*)(ws + off);    off += align256(rowBytes);  // xb0, then ag3
    uint* buf1 = (uint*)(ws + off);    off += align256(rowBytes);  // ag1
    uint* buf2 = (uint*)(ws + off);                                 // ag2

    const int n4 = N_NODES * EMBED_DIM / 4;
    const int nblk4 = (n4 + 255) / 256;
    const int ublk  = (N_UNITS + 255) / 256;   // 2930

    // ---- CSR build: hist+rank -> scan -> XCD-homed atomic-free scatter ----
    hipMemsetAsync(deg, 0, (size_t)N_NODES * 4, stream);
    k_hist_rank<<<ublk, 256, 0, stream>>>((const int4*)dst, (const int4*)src,
                                          deg, (uint4*)ranksrc);
    k_blocksum<<<N_SCAN_BLOCKS, SCAN_BLOCK, 0, stream>>>(deg, bsum);
    k_scan_bsums<<<1, 1024, 0, stream>>>(bsum);
    k_scan_final<<<N_SCAN_BLOCKS, SCAN_BLOCK, 0, stream>>>(deg, bsum, rowptr);
    k_scatter_swz<<<2048, 256, 0, stream>>>((const int4*)dst, (const uint4*)ranksrc,
                                            sd, rowptr, srcw);

    // ---- emb -> bf16 ----
    k_to_bf16<<<nblk4, 256, 0, stream>>>((const float4*)emb, (uint2*)buf0, n4);

    // ---- 3 layers, gather-only, bf16 in/out (buf0->buf1->buf2->buf0) ----
    const int lblk = (N_NODES + 3) / 4;
    k_layer<<<lblk, 256, 0, stream>>>((const uint4*)buf0, rowptr, srcw, (uint4*)buf1);
    k_layer<<<lblk, 256, 0, stream>>>((const uint4*)buf1, rowptr, srcw, (uint4*)buf2);
    k_layer<<<lblk, 256, 0, stream>>>((const uint4*)buf2, rowptr, srcw, (uint4*)buf0);

    // ---- combine ----
    k_combine<<<nblk4, 256, 0, stream>>>((const float4*)emb, (const uint2*)buf1,
                                         (const uint2*)buf2, (const uint2*)buf0,
                                         (float4*)out, n4);
}